// Round 10
// baseline (6742.519 us; speedup 1.0000x reference)
//
#include <hip/hip_runtime.h>
#include <math.h>

// ---------------------------------------------------------------------------
// 4-layer LSTM, B=64 T=512 D=H=1024. Persistent cooperative kernel, wavefront
// schedule (layer l works on t = s - l). Round-10 = round-9 structure with
// the register-spill fix (r9's WRITE_SIZE 2.18GB = scratch traffic):
//   - __launch_bounds__(512, 1): per-wave cap 256+ unified regs (8 waves/CU
//     x ~220 = ~1760 <= 2048 pool), so the ~200-reg demand fits w/o spill.
//     (r5 at cap ~190 didn't spill; r9's ~210 did; r8's 4-wave 390/wave
//     config failed to LAUNCH -- this config keeps 8 waves, demand ~200.)
//   - Inner loop: per-mt {1 ds_read_b128 -> 2 MFMA} instead of a[4] batch
//     (12 fewer live VGPRs, same ILP after scheduling).
// Unchanged from r9 (verified): wave role {mat x gatepair x Khalf}, bw[2][16]
// =128 regs, acc[4][2]=32; staging [mat][kh][64b][64h] 32KB chunks XOR-
// swizzled ((b&7)<<4), distance-1 double-buffer; kh-plane reduction f32[2]
// [64][64] with bp = b ^ ((v&7)<<2) (conflict-free, 34x conflict drop);
// relaxed-agent store/poll single-hop barrier + one acquire fence; fp32 gate
// math; h16 parity double-buffer; c-state in registers.
// ---------------------------------------------------------------------------

#define BSZ 64
#define TSZ 512
#define DSZ 1024
#define HSZ 1024
#define LSZ 4
#define NBLK 256
#define NTHR 512
#define NSTEP (TSZ + LSZ - 1)   // 515
#define BUFB 32768               // bytes per LDS staging buffer

typedef _Float16 half8  __attribute__((ext_vector_type(8)));
typedef _Float16 half4  __attribute__((ext_vector_type(4)));
typedef _Float16 half2v __attribute__((ext_vector_type(2)));
typedef float    f32x4  __attribute__((ext_vector_type(4)));
typedef float    f32x8  __attribute__((ext_vector_type(8)));

// workspace layout (bytes)
constexpr size_t N_X  = (size_t)BSZ * TSZ * DSZ;       // halfs
constexpr size_t N_H  = (size_t)2 * LSZ * BSZ * HSZ;   // halfs (h double buffer)
constexpr size_t OFF_X     = 0;
constexpr size_t OFF_H     = OFF_X + N_X * 2;
constexpr size_t OFF_FLAGS = OFF_H + N_H * 2;          // 256 flags, 64B apart
constexpr size_t BAR_BYTES = (size_t)NBLK * 64;

__device__ inline float sigmoidf_(float x) { return 1.0f / (1.0f + expf(-x)); }

// Single-hop all-poll grid barrier (r6-r9-verified). Entry syncthreads drains
// this block's global stores. Post own flag (relaxed agent); threads 0..255
// poll the 256 flags in parallel; after all polls complete, ONE acquire
// fence, then syncthreads.
__device__ inline void gbar(unsigned* flags, unsigned tgt) {
  __syncthreads();
  const int t = threadIdx.x;
  if (t == 0)
    __hip_atomic_store(&flags[(size_t)blockIdx.x * 16], tgt, __ATOMIC_RELAXED,
                       __HIP_MEMORY_SCOPE_AGENT);
  if (t < NBLK) {
    while (__hip_atomic_load(&flags[(size_t)t * 16], __ATOMIC_RELAXED,
                             __HIP_MEMORY_SCOPE_AGENT) < tgt)
      __builtin_amdgcn_s_sleep(2);
  }
  __syncthreads();
  if (t == 0) __builtin_amdgcn_fence(__ATOMIC_ACQUIRE, "agent");
  __syncthreads();
}

__global__ __launch_bounds__(NTHR, 1) void lstm_persistent(
    const float* __restrict__ xin, const float* __restrict__ Wih,
    const float* __restrict__ Whh, const float* __restrict__ bih,
    const float* __restrict__ bhh, float* __restrict__ out,
    char* __restrict__ ws)
{
  _Float16* x16   = (_Float16*)(ws + OFF_X);
  _Float16* h16   = (_Float16*)(ws + OFF_H);
  unsigned* flags = (unsigned*)(ws + OFF_FLAGS);

  const int tid  = threadIdx.x;
  const int gtid = blockIdx.x * NTHR + tid;
  const int lane = tid & 63;
  const int w    = tid >> 6;        // wave 0..7
  const int mat  = w >> 2;          // 0 = input-side, 1 = recurrent
  const int rp   = (w >> 1) & 1;    // gate pair (gates 2rp, 2rp+1)
  const int kh   = w & 1;           // K-half (512 k's)
  const int ln15 = lane & 15;
  const int lq   = lane >> 4;

  const int l  = blockIdx.x >> 6;   // layer
  const int cc = blockIdx.x & 63;   // column chunk (16 H-cols)
  const int c0 = cc * 16;

  // ---- weight preload into registers (fp32 -> fp16, one time) ----
  // B-frag (r3/r5-verified): lane holds W[row = gate 2rp+gl, col c0+ln15]
  // at k = kh*512 + ks*32 + lq*8 + 0..7. bw[gl][ks] = 128 regs.
  const float* Wsel = mat ? Whh : Wih;
  half8 bw[2][16];
#pragma unroll
  for (int gl = 0; gl < 2; ++gl) {
    const float* wrow =
        Wsel + (size_t)(l * 4096 + (rp * 2 + gl) * 1024 + c0 + ln15) * 1024 +
        kh * 512;
#pragma unroll
    for (int ks = 0; ks < 16; ++ks) {
      f32x8 f = *(const f32x8*)(wrow + ks * 32 + lq * 8);
      bw[gl][ks] = __builtin_convertvector(f, half8);
    }
  }

  // ---- gate-math ownership: batch row gb, column pair gc/gc+1 ----
  const int gb = tid & 63;
  const int gc = (tid >> 6) * 2;    // even col 0..14
  float bsg[4][2];
#pragma unroll
  for (int g = 0; g < 4; ++g) {
    const int bb = l * 4096 + g * 1024 + c0 + gc;
    bsg[g][0] = bih[bb] + bhh[bb];
    bsg[g][1] = bih[bb + 1] + bhh[bb + 1];
  }
  float cr0 = 0.f, cr1 = 0.f;       // block-private c-state (registers)

  // ---- precomputed staging decomposition (step-invariant) ----
  // chunk layout: [mat][kh][64 b][64 halfs], 32KB; swizzle ((b&7)<<4).
  int st_mat[4], st_b[4], st_so[4], st_ds[4];
#pragma unroll
  for (int it = 0; it < 4; ++it) {
    const int idx = it * NTHR + tid;        // 0..2047 16B-slots
    st_mat[it] = idx >> 10;
    const int khs = (idx >> 9) & 1;
    const int b   = (idx >> 3) & 63;
    const int sl  = idx & 7;
    st_b[it]  = b;
    st_so[it] = khs * 1024 + sl * 16;       // byte offset within source row
    st_ds[it] = st_mat[it] * 16384 + khs * 8192 + b * 128 +
                ((sl * 16) ^ ((b & 7) << 4));
  }

  // ---- pre-phase: cast x to fp16, zero h — relaxed agent stores ----
  {
    const f32x4* s4 = (const f32x4*)xin;
    unsigned long long* xu = (unsigned long long*)x16;
    for (int i = gtid; i < (int)(N_X / 4); i += NBLK * NTHR) {
      half4 v = __builtin_convertvector(s4[i], half4);
      __hip_atomic_store(&xu[i], __builtin_bit_cast(unsigned long long, v),
                         __ATOMIC_RELAXED, __HIP_MEMORY_SCOPE_AGENT);
    }
    unsigned long long* hz = (unsigned long long*)h16;
    for (int i = gtid; i < (int)(N_H / 4); i += NBLK * NTHR)
      __hip_atomic_store(&hz[i], 0ull, __ATOMIC_RELAXED,
                         __HIP_MEMORY_SCOPE_AGENT);
  }
  unsigned btgt = 1;
  gbar(flags, btgt++);

  // ---- LDS: 2 staging buffers (32KB each); planes overlay buf0 ----
  __shared__ __align__(16) char smem[2 * BUFB];
  float* pl = (float*)smem;        // f32[2][64][64] after final compute sync

  const int lm1 = (l > 0) ? (l - 1) : 0;

  for (int s = 0; s < NSTEP; ++s) {
    const int t = s - l;
    if (t >= 0 && t < TSZ) {
      const int prevslot = (s + 1) & 1;
      const _Float16* hin  = h16 + (size_t)prevslot * (LSZ * BSZ * HSZ) +
                             (size_t)lm1 * (BSZ * HSZ);
      const _Float16* hown = h16 + (size_t)prevslot * (LSZ * BSZ * HSZ) +
                             (size_t)l * (BSZ * HSZ);
      const _Float16* base0 = (l == 0) ? x16 + (size_t)t * DSZ : hin;
      const size_t    str0  = (l == 0) ? (size_t)TSZ * DSZ : (size_t)HSZ;

      // stage one chunk: K[kc*64..+64) of both K-halves, both mats
      auto stage_load = [&](int kc, half8 (&v)[4]) {
#pragma unroll
        for (int it = 0; it < 4; ++it) {
          const _Float16* rb = st_mat[it] ? hown + (size_t)st_b[it] * HSZ
                                          : base0 + (size_t)st_b[it] * str0;
          v[it] = *(const half8*)((const char*)rb + kc * 128 + st_so[it]);
        }
      };
      auto stage_write = [&](half8 (&v)[4], int bsel) {
#pragma unroll
        for (int it = 0; it < 4; ++it)
          *(half8*)(smem + bsel * BUFB + st_ds[it]) = v[it];
      };

      f32x4 acc[4][2] = {};   // [mt][gl]
      half8 vs[4];

      stage_load(0, vs);
      stage_write(vs, 0);
      __syncthreads();

      const int rdoff = mat * 16384 + kh * 8192;
#pragma unroll
      for (int kc = 0; kc < 8; ++kc) {
        if (kc < 7) stage_load(kc + 1, vs);
        const char* rdb = smem + (kc & 1) * BUFB + rdoff;
#pragma unroll
        for (int ksl = 0; ksl < 2; ++ksl) {
#pragma unroll
          for (int mt = 0; mt < 4; ++mt) {
            const int row = mt * 16 + ln15;
            const half8 a = *(const half8*)(rdb + row * 128 +
                                            ((ksl * 64 + lq * 16) ^
                                             ((row & 7) << 4)));
            acc[mt][0] = __builtin_amdgcn_mfma_f32_16x16x32_f16(
                a, bw[0][kc * 2 + ksl], acc[mt][0], 0, 0, 0);
            acc[mt][1] = __builtin_amdgcn_mfma_f32_16x16x32_f16(
                a, bw[1][kc * 2 + ksl], acc[mt][1], 0, 0, 0);
          }
        }
        if (kc < 7) stage_write(vs, (kc + 1) & 1);
        __syncthreads();
      }

      // ---- kh-plane reduction (mat0 writes, mat1 accumulates) ----
      // C/D map (r3-verified): C row = batch = mt*16+lq*4+r,
      // C col = gate-row v = (2rp+gl)*16+ln15. bp = b ^ ((v&7)<<2).
      if (mat == 0) {
#pragma unroll
        for (int mt = 0; mt < 4; ++mt)
#pragma unroll
          for (int gl = 0; gl < 2; ++gl) {
            const int v  = (rp * 2 + gl) * 16 + ln15;
            const int bp = (mt * 16 + lq * 4) ^ ((ln15 & 7) << 2);
            *(f32x4*)&pl[kh * 4096 + v * 64 + bp] = acc[mt][gl];
          }
      }
      __syncthreads();
      if (mat == 1) {
#pragma unroll
        for (int mt = 0; mt < 4; ++mt)
#pragma unroll
          for (int gl = 0; gl < 2; ++gl) {
            const int v  = (rp * 2 + gl) * 16 + ln15;
            const int bp = (mt * 16 + lq * 4) ^ ((ln15 & 7) << 2);
            f32x4* p = (f32x4*)&pl[kh * 4096 + v * 64 + bp];
            *p = *p + acc[mt][gl];
          }
      }
      __syncthreads();

      // ---- gate math (fp32): thread owns (gb, cols gc/gc+1) ----
      {
        float z[4][2];
#pragma unroll
        for (int g = 0; g < 4; ++g)
#pragma unroll
          for (int j = 0; j < 2; ++j) {
            const int v  = g * 16 + gc + j;
            const int bp = gb ^ ((v & 7) << 2);
            z[g][j] = pl[0 * 4096 + v * 64 + bp] +
                      pl[1 * 4096 + v * 64 + bp] + bsg[g][j];
          }
        float cn0 = sigmoidf_(z[1][0]) * cr0 +
                    sigmoidf_(z[0][0]) * tanhf(z[2][0]);
        float cn1 = sigmoidf_(z[1][1]) * cr1 +
                    sigmoidf_(z[0][1]) * tanhf(z[2][1]);
        float hn0 = sigmoidf_(z[3][0]) * tanhf(cn0);
        float hn1 = sigmoidf_(z[3][1]) * tanhf(cn1);
        cr0 = cn0; cr1 = cn1;
        half2v hv; hv[0] = (_Float16)hn0; hv[1] = (_Float16)hn1;
        const size_t ho = (size_t)(s & 1) * (LSZ * BSZ * HSZ) +
                          (size_t)l * (BSZ * HSZ) + (size_t)gb * HSZ + c0 + gc;
        __hip_atomic_store((unsigned*)(h16 + ho),
                           __builtin_bit_cast(unsigned, hv),
                           __ATOMIC_RELAXED, __HIP_MEMORY_SCOPE_AGENT);
        if (l == LSZ - 1 && t == TSZ - 1) {
          out[(size_t)gb * HSZ + c0 + gc]     = hn0;
          out[(size_t)gb * HSZ + c0 + gc + 1] = hn1;
        }
      }
    }
    gbar(flags, btgt++);
  }
}

extern "C" void kernel_launch(void* const* d_in, const int* in_sizes, int n_in,
                              void* d_out, int out_size, void* d_ws, size_t ws_size,
                              hipStream_t stream) {
  const float* x   = (const float*)d_in[0];
  const float* Wih = (const float*)d_in[1];
  const float* Whh = (const float*)d_in[2];
  const float* bih = (const float*)d_in[3];
  const float* bhh = (const float*)d_in[4];
  float* out = (float*)d_out;
  char*  ws  = (char*)d_ws;

  // barrier flags zeroed every call (captured in graph -> re-zeroed per replay)
  hipMemsetAsync(ws + OFF_FLAGS, 0, BAR_BYTES, stream);

  void* args[] = {(void*)&x, (void*)&Wih, (void*)&Whh, (void*)&bih,
                  (void*)&bhh, (void*)&out, (void*)&ws};
  hipLaunchCooperativeKernel((const void*)lstm_persistent, dim3(NBLK), dim3(NTHR),
                             args, 0, stream);
}

// Round 11
// 5771.289 us; speedup vs baseline: 1.1683x; 1.1683x over previous
//
#include <hip/hip_runtime.h>
#include <math.h>

// ---------------------------------------------------------------------------
// 4-layer LSTM, B=64 T=512 D=H=1024. Persistent cooperative kernel, wavefront
// schedule (layer l works on t = s - l). Round-11 = round-10 structure with
// the VGPR-class demand cut (r9/r10 spilled ~2GB scratch; launch_bounds was
// not the lever -- 8-wave blocks hard-cap at 256 unified regs/wave):
//   - Staging via __builtin_amdgcn_global_load_lds (width 16): removes the
//     vs[] registers, st_ds/st_so arrays and all ds_write addressing (~30
//     VGPRs of class-constrained demand). T21 discipline: LINEAR LDS dest
//     (wave-uniform base + lane*16; mat/kh are wave-uniform per call,
//     b=tid>>3, sl=tid&7), INVERSE-swizzled global source ((sl^(b&7))*16),
//     read-side swizzle unchanged -- swizzle is the same involution on both
//     sides.
//   - Fast gate transcendentals: __expf + v_rcp based sigmoid/tanh (libm
//     tanhf/expf inline large polynomials = register pressure + VALU).
//     |err| ~1e-6 vs 2.75e-3 threshold (current absmax 4.9e-4).
// Unchanged from r10 (verified): wave role {mat x gatepair x Khalf},
// bw[2][16]=128 regs, acc[4][2]; chunk layout [mat][kh][64b][64h] 32KB,
// double-buffered; kh-plane reduction f32[2][64][64] with bp=b^((v&7)<<2)
// (conflict-free, 34x drop r5->r9); relaxed-agent store/poll single-hop
// barrier + one acquire fence; fp32 gate math; h16 parity double-buffer;
// c-state in registers.
// ---------------------------------------------------------------------------

#define BSZ 64
#define TSZ 512
#define DSZ 1024
#define HSZ 1024
#define LSZ 4
#define NBLK 256
#define NTHR 512
#define NSTEP (TSZ + LSZ - 1)   // 515
#define BUFB 32768               // bytes per LDS staging buffer

typedef _Float16 half8  __attribute__((ext_vector_type(8)));
typedef _Float16 half4  __attribute__((ext_vector_type(4)));
typedef _Float16 half2v __attribute__((ext_vector_type(2)));
typedef float    f32x4  __attribute__((ext_vector_type(4)));
typedef float    f32x8  __attribute__((ext_vector_type(8)));

// workspace layout (bytes)
constexpr size_t N_X  = (size_t)BSZ * TSZ * DSZ;       // halfs
constexpr size_t N_H  = (size_t)2 * LSZ * BSZ * HSZ;   // halfs (h double buffer)
constexpr size_t OFF_X     = 0;
constexpr size_t OFF_H     = OFF_X + N_X * 2;
constexpr size_t OFF_FLAGS = OFF_H + N_H * 2;          // 256 flags, 64B apart
constexpr size_t BAR_BYTES = (size_t)NBLK * 64;

// fast gates: v_exp/v_rcp based; graceful at extremes (exp underflow -> 0,
// clamp before overflow). |rel err| ~1e-6.
__device__ inline float fsig(float x) {
  return __builtin_amdgcn_rcpf(1.0f + __expf(-x));
}
__device__ inline float ftanh(float x) {
  float e = __expf(fminf(2.0f * x, 80.0f));   // x<=-? : e->0 gives -1 exactly
  return 1.0f - 2.0f * __builtin_amdgcn_rcpf(e + 1.0f);
}

__device__ inline void gload16(const void* g, void* l) {
  __builtin_amdgcn_global_load_lds(
      (const __attribute__((address_space(1))) void*)g,
      (__attribute__((address_space(3))) void*)l, 16, 0, 0);
}

// Single-hop all-poll grid barrier (r6-r10-verified). Entry syncthreads
// drains this block's global stores (and outstanding global_load_lds via
// vmcnt(0)). Post own flag (relaxed agent); threads 0..255 poll the 256
// flags in parallel; after all polls complete, ONE acquire fence, then
// syncthreads.
__device__ inline void gbar(unsigned* flags, unsigned tgt) {
  __syncthreads();
  const int t = threadIdx.x;
  if (t == 0)
    __hip_atomic_store(&flags[(size_t)blockIdx.x * 16], tgt, __ATOMIC_RELAXED,
                       __HIP_MEMORY_SCOPE_AGENT);
  if (t < NBLK) {
    while (__hip_atomic_load(&flags[(size_t)t * 16], __ATOMIC_RELAXED,
                             __HIP_MEMORY_SCOPE_AGENT) < tgt)
      __builtin_amdgcn_s_sleep(2);
  }
  __syncthreads();
  if (t == 0) __builtin_amdgcn_fence(__ATOMIC_ACQUIRE, "agent");
  __syncthreads();
}

__global__ __launch_bounds__(NTHR, 1) void lstm_persistent(
    const float* __restrict__ xin, const float* __restrict__ Wih,
    const float* __restrict__ Whh, const float* __restrict__ bih,
    const float* __restrict__ bhh, float* __restrict__ out,
    char* __restrict__ ws)
{
  _Float16* x16   = (_Float16*)(ws + OFF_X);
  _Float16* h16   = (_Float16*)(ws + OFF_H);
  unsigned* flags = (unsigned*)(ws + OFF_FLAGS);

  const int tid  = threadIdx.x;
  const int gtid = blockIdx.x * NTHR + tid;
  const int lane = tid & 63;
  const int w    = tid >> 6;        // wave 0..7
  const int mat  = w >> 2;          // 0 = input-side, 1 = recurrent
  const int rp   = (w >> 1) & 1;    // gate pair (gates 2rp, 2rp+1)
  const int kh   = w & 1;           // K-half (512 k's)
  const int ln15 = lane & 15;
  const int lq   = lane >> 4;

  const int l  = blockIdx.x >> 6;   // layer
  const int cc = blockIdx.x & 63;   // column chunk (16 H-cols)
  const int c0 = cc * 16;

  // ---- weight preload into registers (fp32 -> fp16, one time) ----
  // B-frag (r3/r5-verified): lane holds W[row = gate 2rp+gl, col c0+ln15]
  // at k = kh*512 + ks*32 + lq*8 + 0..7. bw[gl][ks] = 128 regs.
  const float* Wsel = mat ? Whh : Wih;
  half8 bw[2][16];
#pragma unroll
  for (int gl = 0; gl < 2; ++gl) {
    const float* wrow =
        Wsel + (size_t)(l * 4096 + (rp * 2 + gl) * 1024 + c0 + ln15) * 1024 +
        kh * 512;
#pragma unroll
    for (int ks = 0; ks < 16; ++ks) {
      f32x8 f = *(const f32x8*)(wrow + ks * 32 + lq * 8);
      bw[gl][ks] = __builtin_convertvector(f, half8);
    }
  }

  // ---- gate-math ownership: batch row gb, column pair gc/gc+1 ----
  const int gb = tid & 63;
  const int gc = (tid >> 6) * 2;    // even col 0..14
  float bsg[4][2];
#pragma unroll
  for (int g = 0; g < 4; ++g) {
    const int bb = l * 4096 + g * 1024 + c0 + gc;
    bsg[g][0] = bih[bb] + bhh[bb];
    bsg[g][1] = bih[bb + 1] + bhh[bb + 1];
  }
  float cr0 = 0.f, cr1 = 0.f;       // block-private c-state (registers)

  // ---- staging decomposition (step-invariant, scalar) ----
  // Chunk layout: [mat][kh][b(64)][8 slots x 16B] = 32KB, LDS LINEAR.
  // Per gload16 call: (mat,kh) wave-uniform; lane covers b=tid>>3, sl=tid&7.
  // Source slot pre-swizzled: sl_g = sl ^ (b&7)  (read applies same XOR).
  const int sb   = tid >> 3;                        // my staging batch row
  const int pswl = ((tid & 7) ^ (sb & 7)) << 4;     // swizzled source slot*16
  const int dstb = (tid >> 6) << 10;                // wave LDS base (w*1024)

  // ---- pre-phase: cast x to fp16, zero h — relaxed agent stores ----
  {
    const f32x4* s4 = (const f32x4*)xin;
    unsigned long long* xu = (unsigned long long*)x16;
    for (int i = gtid; i < (int)(N_X / 4); i += NBLK * NTHR) {
      half4 v = __builtin_convertvector(s4[i], half4);
      __hip_atomic_store(&xu[i], __builtin_bit_cast(unsigned long long, v),
                         __ATOMIC_RELAXED, __HIP_MEMORY_SCOPE_AGENT);
    }
    unsigned long long* hz = (unsigned long long*)h16;
    for (int i = gtid; i < (int)(N_H / 4); i += NBLK * NTHR)
      __hip_atomic_store(&hz[i], 0ull, __ATOMIC_RELAXED,
                         __HIP_MEMORY_SCOPE_AGENT);
  }
  unsigned btgt = 1;
  gbar(flags, btgt++);

  // ---- LDS: 2 staging buffers (32KB each); planes overlay buf0 ----
  __shared__ __align__(16) char smem[2 * BUFB];
  float* pl = (float*)smem;        // f32[2][64][64] after final compute sync

  const int lm1 = (l > 0) ? (l - 1) : 0;

  for (int s = 0; s < NSTEP; ++s) {
    const int t = s - l;
    if (t >= 0 && t < TSZ) {
      const int prevslot = (s + 1) & 1;
      const _Float16* hin  = h16 + (size_t)prevslot * (LSZ * BSZ * HSZ) +
                             (size_t)lm1 * (BSZ * HSZ);
      const _Float16* hown = h16 + (size_t)prevslot * (LSZ * BSZ * HSZ) +
                             (size_t)l * (BSZ * HSZ);
      const _Float16* base0 = (l == 0) ? x16 + (size_t)t * DSZ : hin;
      const size_t    str0  = (l == 0) ? (size_t)TSZ * DSZ : (size_t)HSZ;

      // my two source rows for staging (mat0-side, mat1-side), + swizzle
      const char* p0 = (const char*)(base0 + (size_t)sb * str0) + pswl;
      const char* p1 = (const char*)(hown + (size_t)sb * HSZ) + pswl;

      // stage one chunk (K[kc*64..+64) of both K-halves, both mats) into
      // buf[bsel] via async global->LDS; drained by the next __syncthreads.
      auto stage = [&](int kc, int bsel) {
        const char* r0 = p0 + kc * 128;
        const char* r1 = p1 + kc * 128;
        char* d = smem + bsel * BUFB + dstb;
        gload16(r0,        d);           // (mat0, kh0)
        gload16(r0 + 1024, d + 8192);    // (mat0, kh1)
        gload16(r1,        d + 16384);   // (mat1, kh0)
        gload16(r1 + 1024, d + 24576);   // (mat1, kh1)
      };

      f32x4 acc[4][2] = {};   // [mt][gl]

      stage(0, 0);
      __syncthreads();

      const int rdoff = mat * 16384 + kh * 8192;
#pragma unroll
      for (int kc = 0; kc < 8; ++kc) {
        if (kc < 7) stage(kc + 1, (kc + 1) & 1);
        const char* rdb = smem + (kc & 1) * BUFB + rdoff;
#pragma unroll
        for (int ksl = 0; ksl < 2; ++ksl) {
#pragma unroll
          for (int mt = 0; mt < 4; ++mt) {
            const int row = mt * 16 + ln15;
            const half8 a = *(const half8*)(rdb + row * 128 +
                                            ((ksl * 64 + lq * 16) ^
                                             ((row & 7) << 4)));
            acc[mt][0] = __builtin_amdgcn_mfma_f32_16x16x32_f16(
                a, bw[0][kc * 2 + ksl], acc[mt][0], 0, 0, 0);
            acc[mt][1] = __builtin_amdgcn_mfma_f32_16x16x32_f16(
                a, bw[1][kc * 2 + ksl], acc[mt][1], 0, 0, 0);
          }
        }
        __syncthreads();
      }

      // ---- kh-plane reduction (mat0 writes, mat1 accumulates) ----
      // C/D map (r3-verified): C row = batch = mt*16+lq*4+r,
      // C col = gate-row v = (2rp+gl)*16+ln15. bp = b ^ ((v&7)<<2).
      if (mat == 0) {
#pragma unroll
        for (int mt = 0; mt < 4; ++mt)
#pragma unroll
          for (int gl = 0; gl < 2; ++gl) {
            const int v  = (rp * 2 + gl) * 16 + ln15;
            const int bp = (mt * 16 + lq * 4) ^ ((ln15 & 7) << 2);
            *(f32x4*)&pl[kh * 4096 + v * 64 + bp] = acc[mt][gl];
          }
      }
      __syncthreads();
      if (mat == 1) {
#pragma unroll
        for (int mt = 0; mt < 4; ++mt)
#pragma unroll
          for (int gl = 0; gl < 2; ++gl) {
            const int v  = (rp * 2 + gl) * 16 + ln15;
            const int bp = (mt * 16 + lq * 4) ^ ((ln15 & 7) << 2);
            f32x4* p = (f32x4*)&pl[kh * 4096 + v * 64 + bp];
            *p = *p + acc[mt][gl];
          }
      }
      __syncthreads();

      // ---- gate math (fp32): thread owns (gb, cols gc/gc+1) ----
      {
        float z[4][2];
#pragma unroll
        for (int g = 0; g < 4; ++g)
#pragma unroll
          for (int j = 0; j < 2; ++j) {
            const int v  = g * 16 + gc + j;
            const int bp = gb ^ ((v & 7) << 2);
            z[g][j] = pl[0 * 4096 + v * 64 + bp] +
                      pl[1 * 4096 + v * 64 + bp] + bsg[g][j];
          }
        float cn0 = fsig(z[1][0]) * cr0 + fsig(z[0][0]) * ftanh(z[2][0]);
        float cn1 = fsig(z[1][1]) * cr1 + fsig(z[0][1]) * ftanh(z[2][1]);
        float hn0 = fsig(z[3][0]) * ftanh(cn0);
        float hn1 = fsig(z[3][1]) * ftanh(cn1);
        cr0 = cn0; cr1 = cn1;
        half2v hv; hv[0] = (_Float16)hn0; hv[1] = (_Float16)hn1;
        const size_t ho = (size_t)(s & 1) * (LSZ * BSZ * HSZ) +
                          (size_t)l * (BSZ * HSZ) + (size_t)gb * HSZ + c0 + gc;
        __hip_atomic_store((unsigned*)(h16 + ho),
                           __builtin_bit_cast(unsigned, hv),
                           __ATOMIC_RELAXED, __HIP_MEMORY_SCOPE_AGENT);
        if (l == LSZ - 1 && t == TSZ - 1) {
          out[(size_t)gb * HSZ + c0 + gc]     = hn0;
          out[(size_t)gb * HSZ + c0 + gc + 1] = hn1;
        }
      }
    }
    gbar(flags, btgt++);
  }
}

extern "C" void kernel_launch(void* const* d_in, const int* in_sizes, int n_in,
                              void* d_out, int out_size, void* d_ws, size_t ws_size,
                              hipStream_t stream) {
  const float* x   = (const float*)d_in[0];
  const float* Wih = (const float*)d_in[1];
  const float* Whh = (const float*)d_in[2];
  const float* bih = (const float*)d_in[3];
  const float* bhh = (const float*)d_in[4];
  float* out = (float*)d_out;
  char*  ws  = (char*)d_ws;

  // barrier flags zeroed every call (captured in graph -> re-zeroed per replay)
  hipMemsetAsync(ws + OFF_FLAGS, 0, BAR_BYTES, stream);

  void* args[] = {(void*)&x, (void*)&Wih, (void*)&Whh, (void*)&bih,
                  (void*)&bhh, (void*)&out, (void*)&ws};
  hipLaunchCooperativeKernel((const void*)lstm_persistent, dim3(NBLK), dim3(NTHR),
                             args, 0, stream);
}

// Round 12
// 4810.986 us; speedup vs baseline: 1.4015x; 1.1996x over previous
//
#include <hip/hip_runtime.h>
#include <math.h>

// ---------------------------------------------------------------------------
// 4-layer LSTM, B=64 T=512 D=H=1024. Persistent cooperative kernel, wavefront
// schedule (layer l works on t = s - l). Round-12 = round-11 with ONE change:
// the h-store coalescing fix.
//   DIAGNOSIS (r9/r10/r11): WRITE_SIZE byte-identical 2.1845 GB across three
//   different register-pressure kernels => not spill; it is the h16
//   write-through atomic stores. Since r6, gate ownership gb = tid&63 made
//   each wave's 64 lanes store 4B to 64 DIFFERENT rows -> 64 isolated
//   write-through transactions/wave, ~1.84 GB write amplification vs r5's
//   0.35 GB.
//   FIX: revert to r5's mapping gb = tid>>3, gc = (tid&7)*2: lanes 0..7
//   cover 32 contiguous bytes of one row -> 8 coalesced 32B bursts per wave.
//   (Stores stay RELAXED AGENT atomics: write-through visibility is what the
//   inv-only barrier relies on -- no release/writeback exists anywhere.)
// Unchanged from r11 (verified): global_load_lds staging (linear LDS dest,
// inverse-swizzled source), wave role {mat x gatepair x Khalf}, bw[2][16],
// acc[4][2], kh-plane reduction with bp=b^((v&7)<<2), fast gates
// (__expf/rcp), relaxed-agent single-hop barrier + one acquire fence, fp32
// gate math, h16 parity double-buffer, c-state in registers.
// ---------------------------------------------------------------------------

#define BSZ 64
#define TSZ 512
#define DSZ 1024
#define HSZ 1024
#define LSZ 4
#define NBLK 256
#define NTHR 512
#define NSTEP (TSZ + LSZ - 1)   // 515
#define BUFB 32768               // bytes per LDS staging buffer

typedef _Float16 half8  __attribute__((ext_vector_type(8)));
typedef _Float16 half4  __attribute__((ext_vector_type(4)));
typedef _Float16 half2v __attribute__((ext_vector_type(2)));
typedef float    f32x4  __attribute__((ext_vector_type(4)));
typedef float    f32x8  __attribute__((ext_vector_type(8)));

// workspace layout (bytes)
constexpr size_t N_X  = (size_t)BSZ * TSZ * DSZ;       // halfs
constexpr size_t N_H  = (size_t)2 * LSZ * BSZ * HSZ;   // halfs (h double buffer)
constexpr size_t OFF_X     = 0;
constexpr size_t OFF_H     = OFF_X + N_X * 2;
constexpr size_t OFF_FLAGS = OFF_H + N_H * 2;          // 256 flags, 64B apart
constexpr size_t BAR_BYTES = (size_t)NBLK * 64;

// fast gates: v_exp/v_rcp based. |rel err| ~1e-6 (r11-verified: absmax
// unchanged at 4.88e-4).
__device__ inline float fsig(float x) {
  return __builtin_amdgcn_rcpf(1.0f + __expf(-x));
}
__device__ inline float ftanh(float x) {
  float e = __expf(fminf(2.0f * x, 80.0f));
  return 1.0f - 2.0f * __builtin_amdgcn_rcpf(e + 1.0f);
}

__device__ inline void gload16(const void* g, void* l) {
  __builtin_amdgcn_global_load_lds(
      (const __attribute__((address_space(1))) void*)g,
      (__attribute__((address_space(3))) void*)l, 16, 0, 0);
}

// Single-hop all-poll grid barrier (r6-r11-verified). Entry syncthreads
// drains this block's global stores (and outstanding global_load_lds via
// vmcnt(0)). Post own flag (relaxed agent); threads 0..255 poll the 256
// flags in parallel; after all polls complete, ONE acquire fence, then
// syncthreads.
__device__ inline void gbar(unsigned* flags, unsigned tgt) {
  __syncthreads();
  const int t = threadIdx.x;
  if (t == 0)
    __hip_atomic_store(&flags[(size_t)blockIdx.x * 16], tgt, __ATOMIC_RELAXED,
                       __HIP_MEMORY_SCOPE_AGENT);
  if (t < NBLK) {
    while (__hip_atomic_load(&flags[(size_t)t * 16], __ATOMIC_RELAXED,
                             __HIP_MEMORY_SCOPE_AGENT) < tgt)
      __builtin_amdgcn_s_sleep(2);
  }
  __syncthreads();
  if (t == 0) __builtin_amdgcn_fence(__ATOMIC_ACQUIRE, "agent");
  __syncthreads();
}

__global__ __launch_bounds__(NTHR, 1) void lstm_persistent(
    const float* __restrict__ xin, const float* __restrict__ Wih,
    const float* __restrict__ Whh, const float* __restrict__ bih,
    const float* __restrict__ bhh, float* __restrict__ out,
    char* __restrict__ ws)
{
  _Float16* x16   = (_Float16*)(ws + OFF_X);
  _Float16* h16   = (_Float16*)(ws + OFF_H);
  unsigned* flags = (unsigned*)(ws + OFF_FLAGS);

  const int tid  = threadIdx.x;
  const int gtid = blockIdx.x * NTHR + tid;
  const int lane = tid & 63;
  const int w    = tid >> 6;        // wave 0..7
  const int mat  = w >> 2;          // 0 = input-side, 1 = recurrent
  const int rp   = (w >> 1) & 1;    // gate pair (gates 2rp, 2rp+1)
  const int kh   = w & 1;           // K-half (512 k's)
  const int ln15 = lane & 15;
  const int lq   = lane >> 4;

  const int l  = blockIdx.x >> 6;   // layer
  const int cc = blockIdx.x & 63;   // column chunk (16 H-cols)
  const int c0 = cc * 16;

  // ---- weight preload into registers (fp32 -> fp16, one time) ----
  // B-frag (r3/r5-verified): lane holds W[row = gate 2rp+gl, col c0+ln15]
  // at k = kh*512 + ks*32 + lq*8 + 0..7. bw[gl][ks] = 128 regs.
  const float* Wsel = mat ? Whh : Wih;
  half8 bw[2][16];
#pragma unroll
  for (int gl = 0; gl < 2; ++gl) {
    const float* wrow =
        Wsel + (size_t)(l * 4096 + (rp * 2 + gl) * 1024 + c0 + ln15) * 1024 +
        kh * 512;
#pragma unroll
    for (int ks = 0; ks < 16; ++ks) {
      f32x8 f = *(const f32x8*)(wrow + ks * 32 + lq * 8);
      bw[gl][ks] = __builtin_convertvector(f, half8);
    }
  }

  // ---- gate-math ownership (COALESCED, r5 mapping): row gb, cols gc/gc+1 --
  // Wave w covers rows w*8..w*8+7; lanes 0..7 cover 32 contiguous bytes of
  // one row -> h-store coalesces to 8 x 32B bursts per wave.
  const int gb = tid >> 3;          // batch row 0..63
  const int gc = (tid & 7) * 2;     // even col 0..14
  float bsg[4][2];
#pragma unroll
  for (int g = 0; g < 4; ++g) {
    const int bb = l * 4096 + g * 1024 + c0 + gc;
    bsg[g][0] = bih[bb] + bhh[bb];
    bsg[g][1] = bih[bb + 1] + bhh[bb + 1];
  }
  float cr0 = 0.f, cr1 = 0.f;       // block-private c-state (registers)

  // ---- staging decomposition (step-invariant, scalar) ----
  // Chunk layout: [mat][kh][b(64)][8 slots x 16B] = 32KB, LDS LINEAR.
  // Per gload16 call: (mat,kh) wave-uniform; lane covers b=tid>>3, sl=tid&7.
  // Source slot pre-swizzled: sl_g = sl ^ (b&7)  (read applies same XOR).
  const int sb   = tid >> 3;                        // my staging batch row
  const int pswl = ((tid & 7) ^ (sb & 7)) << 4;     // swizzled source slot*16
  const int dstb = (tid >> 6) << 10;                // wave LDS base (w*1024)

  // ---- pre-phase: cast x to fp16, zero h — relaxed agent stores ----
  {
    const f32x4* s4 = (const f32x4*)xin;
    unsigned long long* xu = (unsigned long long*)x16;
    for (int i = gtid; i < (int)(N_X / 4); i += NBLK * NTHR) {
      half4 v = __builtin_convertvector(s4[i], half4);
      __hip_atomic_store(&xu[i], __builtin_bit_cast(unsigned long long, v),
                         __ATOMIC_RELAXED, __HIP_MEMORY_SCOPE_AGENT);
    }
    unsigned long long* hz = (unsigned long long*)h16;
    for (int i = gtid; i < (int)(N_H / 4); i += NBLK * NTHR)
      __hip_atomic_store(&hz[i], 0ull, __ATOMIC_RELAXED,
                         __HIP_MEMORY_SCOPE_AGENT);
  }
  unsigned btgt = 1;
  gbar(flags, btgt++);

  // ---- LDS: 2 staging buffers (32KB each); planes overlay buf0 ----
  __shared__ __align__(16) char smem[2 * BUFB];
  float* pl = (float*)smem;        // f32[2][64][64] after final compute sync

  const int lm1 = (l > 0) ? (l - 1) : 0;

  for (int s = 0; s < NSTEP; ++s) {
    const int t = s - l;
    if (t >= 0 && t < TSZ) {
      const int prevslot = (s + 1) & 1;
      const _Float16* hin  = h16 + (size_t)prevslot * (LSZ * BSZ * HSZ) +
                             (size_t)lm1 * (BSZ * HSZ);
      const _Float16* hown = h16 + (size_t)prevslot * (LSZ * BSZ * HSZ) +
                             (size_t)l * (BSZ * HSZ);
      const _Float16* base0 = (l == 0) ? x16 + (size_t)t * DSZ : hin;
      const size_t    str0  = (l == 0) ? (size_t)TSZ * DSZ : (size_t)HSZ;

      // my two source rows for staging (mat0-side, mat1-side), + swizzle
      const char* p0 = (const char*)(base0 + (size_t)sb * str0) + pswl;
      const char* p1 = (const char*)(hown + (size_t)sb * HSZ) + pswl;

      // stage one chunk (K[kc*64..+64) of both K-halves, both mats) into
      // buf[bsel] via async global->LDS; drained by the next __syncthreads.
      auto stage = [&](int kc, int bsel) {
        const char* r0 = p0 + kc * 128;
        const char* r1 = p1 + kc * 128;
        char* d = smem + bsel * BUFB + dstb;
        gload16(r0,        d);           // (mat0, kh0)
        gload16(r0 + 1024, d + 8192);    // (mat0, kh1)
        gload16(r1,        d + 16384);   // (mat1, kh0)
        gload16(r1 + 1024, d + 24576);   // (mat1, kh1)
      };

      f32x4 acc[4][2] = {};   // [mt][gl]

      stage(0, 0);
      __syncthreads();

      const int rdoff = mat * 16384 + kh * 8192;
#pragma unroll
      for (int kc = 0; kc < 8; ++kc) {
        if (kc < 7) stage(kc + 1, (kc + 1) & 1);
        const char* rdb = smem + (kc & 1) * BUFB + rdoff;
#pragma unroll
        for (int ksl = 0; ksl < 2; ++ksl) {
#pragma unroll
          for (int mt = 0; mt < 4; ++mt) {
            const int row = mt * 16 + ln15;
            const half8 a = *(const half8*)(rdb + row * 128 +
                                            ((ksl * 64 + lq * 16) ^
                                             ((row & 7) << 4)));
            acc[mt][0] = __builtin_amdgcn_mfma_f32_16x16x32_f16(
                a, bw[0][kc * 2 + ksl], acc[mt][0], 0, 0, 0);
            acc[mt][1] = __builtin_amdgcn_mfma_f32_16x16x32_f16(
                a, bw[1][kc * 2 + ksl], acc[mt][1], 0, 0, 0);
          }
        }
        __syncthreads();
      }

      // ---- kh-plane reduction (mat0 writes, mat1 accumulates) ----
      // C/D map (r3-verified): C row = batch = mt*16+lq*4+r,
      // C col = gate-row v = (2rp+gl)*16+ln15. bp = b ^ ((v&7)<<2).
      if (mat == 0) {
#pragma unroll
        for (int mt = 0; mt < 4; ++mt)
#pragma unroll
          for (int gl = 0; gl < 2; ++gl) {
            const int v  = (rp * 2 + gl) * 16 + ln15;
            const int bp = (mt * 16 + lq * 4) ^ ((ln15 & 7) << 2);
            *(f32x4*)&pl[kh * 4096 + v * 64 + bp] = acc[mt][gl];
          }
      }
      __syncthreads();
      if (mat == 1) {
#pragma unroll
        for (int mt = 0; mt < 4; ++mt)
#pragma unroll
          for (int gl = 0; gl < 2; ++gl) {
            const int v  = (rp * 2 + gl) * 16 + ln15;
            const int bp = (mt * 16 + lq * 4) ^ ((ln15 & 7) << 2);
            f32x4* p = (f32x4*)&pl[kh * 4096 + v * 64 + bp];
            *p = *p + acc[mt][gl];
          }
      }
      __syncthreads();

      // ---- gate math (fp32): thread owns (gb, cols gc/gc+1) ----
      {
        float z[4][2];
#pragma unroll
        for (int g = 0; g < 4; ++g)
#pragma unroll
          for (int j = 0; j < 2; ++j) {
            const int v  = g * 16 + gc + j;
            const int bp = gb ^ ((v & 7) << 2);
            z[g][j] = pl[0 * 4096 + v * 64 + bp] +
                      pl[1 * 4096 + v * 64 + bp] + bsg[g][j];
          }
        float cn0 = fsig(z[1][0]) * cr0 + fsig(z[0][0]) * ftanh(z[2][0]);
        float cn1 = fsig(z[1][1]) * cr1 + fsig(z[0][1]) * ftanh(z[2][1]);
        float hn0 = fsig(z[3][0]) * ftanh(cn0);
        float hn1 = fsig(z[3][1]) * ftanh(cn1);
        cr0 = cn0; cr1 = cn1;
        half2v hv; hv[0] = (_Float16)hn0; hv[1] = (_Float16)hn1;
        const size_t ho = (size_t)(s & 1) * (LSZ * BSZ * HSZ) +
                          (size_t)l * (BSZ * HSZ) + (size_t)gb * HSZ + c0 + gc;
        __hip_atomic_store((unsigned*)(h16 + ho),
                           __builtin_bit_cast(unsigned, hv),
                           __ATOMIC_RELAXED, __HIP_MEMORY_SCOPE_AGENT);
        if (l == LSZ - 1 && t == TSZ - 1) {
          out[(size_t)gb * HSZ + c0 + gc]     = hn0;
          out[(size_t)gb * HSZ + c0 + gc + 1] = hn1;
        }
      }
    }
    gbar(flags, btgt++);
  }
}

extern "C" void kernel_launch(void* const* d_in, const int* in_sizes, int n_in,
                              void* d_out, int out_size, void* d_ws, size_t ws_size,
                              hipStream_t stream) {
  const float* x   = (const float*)d_in[0];
  const float* Wih = (const float*)d_in[1];
  const float* Whh = (const float*)d_in[2];
  const float* bih = (const float*)d_in[3];
  const float* bhh = (const float*)d_in[4];
  float* out = (float*)d_out;
  char*  ws  = (char*)d_ws;

  // barrier flags zeroed every call (captured in graph -> re-zeroed per replay)
  hipMemsetAsync(ws + OFF_FLAGS, 0, BAR_BYTES, stream);

  void* args[] = {(void*)&x, (void*)&Wih, (void*)&Whh, (void*)&bih,
                  (void*)&bhh, (void*)&out, (void*)&ws};
  hipLaunchCooperativeKernel((const void*)lstm_persistent, dim3(NBLK), dim3(NTHR),
                             args, 0, stream);
}